// Round 13
// baseline (181.394 us; speedup 1.0000x reference)
//
#include <hip/hip_runtime.h>
#include <math.h>

// Problem constants
#define S_N 16
#define D_N 256
#define H_N 128
#define K_N 32
#define BT  32
#define B_N 16384

typedef __attribute__((ext_vector_type(8))) short bf16x8;
typedef __attribute__((ext_vector_type(4))) short bf16x4;
typedef __attribute__((ext_vector_type(4))) float f32x4;
typedef __attribute__((ext_vector_type(16))) float f32x16;

#define MFMA16(a, b, c) __builtin_amdgcn_mfma_f32_16x16x32_bf16(a, b, c, 0, 0, 0)
#define MFMA32(a, b, c) __builtin_amdgcn_mfma_f32_32x32x16_bf16(a, b, c, 0, 0, 0)
#define SWZ(r) ((unsigned)(((r) & 15) << 4))

static __device__ __forceinline__ unsigned short f2bf(float f) {
  union { float f; unsigned u; } v; v.f = f;
  unsigned r = v.u + 0x7FFFu + ((v.u >> 16) & 1u);  // RNE
  return (unsigned short)(r >> 16);
}
static __device__ __forceinline__ float bf2f(unsigned short u) {
  union { unsigned u; float f; } v; v.u = ((unsigned)u) << 16;
  return v.f;
}

// ---------------- merged pre-pass (unchanged) ----------------
__global__ __launch_bounds__(256)
void lsi_prep(const float* __restrict__ W1, const float* __restrict__ W2,
              const float* __restrict__ Wc1, const float* __restrict__ b2,
              const float* __restrict__ bc1,
              unsigned short* __restrict__ W1t,
              unsigned short* __restrict__ W2t,
              unsigned short* __restrict__ Wft,
              float* __restrict__ bcf)
{
  const int bid = blockIdx.x;
  if (bid < 1024) {
    __shared__ float t[32][33];
    const float* src; unsigned short* dst; int R, C, r0, c0;
    if (bid < 512) {
      int s = bid >> 5, tt = bid & 31;
      R = 256; C = 128; r0 = (tt >> 2) * 32; c0 = (tt & 3) * 32;
      src = W1 + (size_t)s * 256 * 128; dst = W1t + (size_t)s * 128 * 256;
    } else {
      int s = (bid - 512) >> 5, tt = (bid - 512) & 31;
      R = 128; C = 256; r0 = (tt >> 3) * 32; c0 = (tt & 7) * 32;
      src = W2 + (size_t)s * 128 * 256; dst = W2t + (size_t)s * 256 * 128;
    }
    int li = threadIdx.x >> 5, lj = threadIdx.x & 31;
    #pragma unroll
    for (int i = 0; i < 4; ++i)
      t[li + i * 8][lj] = src[(size_t)(r0 + li + i * 8) * C + c0 + lj];
    __syncthreads();
    #pragma unroll
    for (int i = 0; i < 4; ++i)
      dst[(size_t)(c0 + li + i * 8) * R + r0 + lj] = f2bf(t[lj][li + i * 8]);
    return;
  }
  const int q  = bid - 1024;
  const int s  = q >> 3, hb = q & 7;
  const int t  = threadIdx.x;
  const int hh = hb * 16 + (t >> 4);
  const int kb = (t & 15) * 2;
  const float* w2r = W2 + ((size_t)s * H_N + hh) * D_N;
  const float* wc1 = Wc1 + (size_t)s * D_N * K_N;
  float a0 = 0.f, a1 = 0.f;
  for (int d = 0; d < D_N; ++d) {
    float wv = w2r[d];
    a0 = fmaf(wv, wc1[d * K_N + kb], a0);
    a1 = fmaf(wv, wc1[d * K_N + kb + 1], a1);
  }
  Wft[((size_t)s * K_N + kb) * H_N + hh]     = f2bf(a0);
  Wft[((size_t)s * K_N + kb + 1) * H_N + hh] = f2bf(a1);
  if (hb == 0 && t < K_N) {
    float a = bc1[s * K_N + t];
    for (int d = 0; d < D_N; ++d)
      a = fmaf(b2[s * D_N + d], wc1[d * K_N + t], a);
    bcf[s * K_N + t] = a;
  }
}

// ---------------- fused main kernel ----------------
// acc2 ELIMINATED via  sum_s cw.(h.W2) = sum_s (diag(cw).h).W2 : h is scaled
// by cw in LDS, GEMM2 MFMA-accumulates ALL sources directly into out_acc.
// Bias term sum_s cw_s[row].b2_s[col] folded in epilogue from cw history.
// 256-thr blocks (4 waves), BT=32, (256,4): target 4 blocks/CU = 16 waves/CU.
// SPLIT=1: grid 1024 (512 rowgrp x 2 source-halves), partial out; else grid 512.
// Per source, 3 barriers:
//   P1: GEMM1(s+1)->h[other] (16xMFMA32/wave) ; conf(s) (4xMFMA16/wave) -> zp
//   P2: scale h(s) *= cw(s) in LDS ; wsum += cw ; cw history
//   P3: GEMM2(s): out_acc += (cw.h).W2  (16xMFMA32/wave, direct accumulate)
template<int SPLIT>
__global__ __launch_bounds__(256, 4)
void lsi_main(const float* __restrict__ x,
              const float* __restrict__ b1,
              const float* __restrict__ b2,
              const float* __restrict__ Wc2,
              const float* __restrict__ bc2,
              const float* __restrict__ lam,
              const unsigned short* __restrict__ W1t,
              const unsigned short* __restrict__ W2t,
              const unsigned short* __restrict__ Wft,
              const float* __restrict__ bcf,
              float* __restrict__ outp,
              float* __restrict__ pwsum)
{
  __shared__ __align__(16) unsigned short x_lds[BT * D_N];      // 16 KB
  __shared__ __align__(16) unsigned short h_lds[2][BT * H_N];   // 16 KB
  __shared__ float zp_lds[2][BT];
  __shared__ float cwh[16][BT];      // cw history (2 KB)
  __shared__ float wsum_lds[BT];

  const int tid = threadIdx.x;
  const int w   = tid >> 6;       // wave 0..3
  const int l   = tid & 63;
  const int l31 = l & 31;
  const int hi  = l >> 5;
  const int l15 = l & 15;
  const int g   = l >> 4;

  int rb, half, s0, ns;
  if (SPLIT) { rb = blockIdx.x & 511; half = blockIdx.x >> 9; s0 = half * 8; ns = 8; }
  else       { rb = blockIdx.x;       half = 0;               s0 = 0;        ns = 16; }
  const int b0 = rb * BT;

  // ---- stage x tile [32 x 256] -> bf16 LDS (swizzled [brow][k]) ----
  {
    int row = tid >> 3;                 // 0..31
    int c0  = (tid & 7) * 32;
    const float* xr = x + (size_t)(b0 + row) * D_N + c0;
    #pragma unroll
    for (int cc = 0; cc < 4; ++cc) {
      float4 f0 = *(const float4*)(xr + cc * 8);
      float4 f1 = *(const float4*)(xr + cc * 8 + 4);
      bf16x8 u;
      u[0] = f2bf(f0.x); u[1] = f2bf(f0.y); u[2] = f2bf(f0.z); u[3] = f2bf(f0.w);
      u[4] = f2bf(f1.x); u[5] = f2bf(f1.y); u[6] = f2bf(f1.z); u[7] = f2bf(f1.w);
      unsigned off = (unsigned)(row * 512 + (c0 + cc * 8) * 2) ^ SWZ(row);
      *(bf16x8*)((char*)x_lds + off) = u;
    }
  }
  if (tid < BT) wsum_lds[tid] = 0.f;

  f32x16 oa0, oa1;   // out_acc: wave dcols [64w,64w+64) as 2 tiles; C[dcol][brow]
  #pragma unroll
  for (int i = 0; i < 16; ++i) { oa0[i] = 0.f; oa1[i] = 0.f; }

  // GEMM1(s) transposed: C[hcol][brow]; wave w -> hcols [32w,32w+32)
  auto do_gemm1 = [&](int s, unsigned short* hw) {
    f32x16 a1;
    #pragma unroll
    for (int i = 0; i < 16; ++i) a1[i] = 0.f;
    const unsigned short* A1 = W1t + ((size_t)s * H_N + w * 32 + l31) * D_N + hi * 8;
    #pragma unroll
    for (int kf = 0; kf < 16; ++kf) {
      bf16x8 aw = *(const bf16x8*)(A1 + kf * 16);
      bf16x8 bx = *(const bf16x8*)((const char*)x_lds +
                    ((unsigned)(l31 * 512 + kf * 32 + hi * 16) ^ SWZ(l31)));
      a1 = MFMA32(aw, bx, a1);
    }
    #pragma unroll
    for (int q = 0; q < 4; ++q) {
      f32x4 b4 = *(const f32x4*)(b1 + s * H_N + w * 32 + q * 8 + hi * 4);
      bf16x4 hv;
      #pragma unroll
      for (int i = 0; i < 4; ++i)
        hv[i] = (short)f2bf(fmaxf(a1[q * 4 + i] + b4[i], 0.f));
      unsigned off = (unsigned)(l31 * 256 + (w * 32 + q * 8 + hi * 4) * 2) ^ SWZ(l31);
      *(bf16x4*)((char*)hw + off) = hv;
    }
  };

  __syncthreads();               // x staged
  do_gemm1(s0, h_lds[0]);
  __syncthreads();               // h(s0) ready

  for (int si = 0; si < ns; ++si) {
    const int s = s0 + si;
    const unsigned short* hr = (const unsigned short*)h_lds[si & 1];

    // ---- P1: GEMM1(s+1) || conf(s) ----
    if (si + 1 < ns) do_gemm1(s + 1, h_lds[(si + 1) & 1]);
    {
      // conf(s): wave -> (bt = w>>1 brow-tile, kt = w&1 k-tile); C[k][brow]
      const int bt = w >> 1, kt = w & 1;
      f32x4 c3 = (f32x4){0.f, 0.f, 0.f, 0.f};
      const unsigned short* Af = Wft + ((size_t)s * K_N + kt * 16 + l15) * H_N + g * 8;
      #pragma unroll
      for (int ks = 0; ks < 4; ++ks) {
        int brow = bt * 16 + l15;
        bf16x8 hb = *(const bf16x8*)((const char*)hr +
                      ((unsigned)(brow * 256 + ks * 64 + g * 16) ^ SWZ(brow)));
        c3 = MFMA16(*(const bf16x8*)(Af + ks * 32), hb, c3);
      }
      f32x4 bc4 = *(const f32x4*)(bcf + s * K_N + kt * 16 + g * 4);
      f32x4 wc4 = *(const f32x4*)(Wc2 + s * K_N + kt * 16 + g * 4);
      float zz = 0.f;
      #pragma unroll
      for (int i = 0; i < 4; ++i)
        zz += fmaxf(c3[i] + bc4[i], 0.f) * wc4[i];
      zz += __shfl_xor(zz, 16);
      zz += __shfl_xor(zz, 32);
      if (l < 16) zp_lds[kt][bt * 16 + l] = zz;
    }
    __syncthreads();   // barA: zp ready, h(s+1) written

    // ---- P2: cw(s); scale h(s) in LDS; wsum; history ----
    {
      unsigned short* hm = h_lds[si & 1];
      const int r  = tid >> 3;
      const int c0 = (tid & 7) * 32;     // byte col offset (16 bf16)
      float cv = lam[s] / (1.f + __expf(-(zp_lds[0][r] + zp_lds[1][r] + bc2[s])));
      unsigned off0 = (unsigned)(r * 256 + c0) ^ SWZ(r);
      unsigned off1 = (unsigned)(r * 256 + c0 + 16) ^ SWZ(r);
      bf16x8 v0 = *(const bf16x8*)((const char*)hm + off0);
      bf16x8 v1 = *(const bf16x8*)((const char*)hm + off1);
      #pragma unroll
      for (int j = 0; j < 8; ++j) {
        v0[j] = (short)f2bf(bf2f((unsigned short)v0[j]) * cv);
        v1[j] = (short)f2bf(bf2f((unsigned short)v1[j]) * cv);
      }
      *(bf16x8*)((char*)hm + off0) = v0;
      *(bf16x8*)((char*)hm + off1) = v1;
      if ((tid & 7) == 0) {
        wsum_lds[r] += cv;
        cwh[si][r] = cv;
      }
    }
    __syncthreads();   // barB: h(s) scaled

    // ---- P3: GEMM2(s): out_acc += (cw.h).W2 ; direct MFMA accumulate ----
    {
      const unsigned short* A2 = W2t + ((size_t)s * D_N + w * 64 + l31) * H_N + hi * 8;
      #pragma unroll
      for (int kf = 0; kf < 8; ++kf) {
        bf16x8 hb = *(const bf16x8*)((const char*)hr +
                      ((unsigned)(l31 * 256 + kf * 32 + hi * 16) ^ SWZ(l31)));
        oa0 = MFMA32(*(const bf16x8*)(A2 + kf * 16), hb, oa0);
        oa1 = MFMA32(*(const bf16x8*)(A2 + 32 * H_N + kf * 16), hb, oa1);
      }
    }
    __syncthreads();   // barC: h(s) free for GEMM1(s+2)
  }

  // ---- epilogue: bias fold  out += sum_s cw_s[brow].b2_s[dcol] ----
  #pragma unroll
  for (int q = 0; q < 4; ++q) {
    const int dc0 = w * 64 + q * 8 + hi * 4;
    for (int si = 0; si < ns; ++si) {
      const float c = cwh[si][l31];
      f32x4 ba = *(const f32x4*)(b2 + (s0 + si) * D_N + dc0);
      f32x4 bb = *(const f32x4*)(b2 + (s0 + si) * D_N + dc0 + 32);
      #pragma unroll
      for (int i = 0; i < 4; ++i) {
        oa0[q * 4 + i] += c * ba[i];
        oa1[q * 4 + i] += c * bb[i];
      }
    }
  }
  if (!SPLIT) {
    const float winv = 1.f / (wsum_lds[l31] + 1e-6f);
    #pragma unroll
    for (int i = 0; i < 16; ++i) { oa0[i] *= winv; oa1[i] *= winv; }
  }

  // ---- store via per-wave LDS transpose (x_lds/h_lds free) ----
  {
    float* tb = (w < 2) ? ((float*)x_lds + w * 1152)
                        : ((float*)h_lds + (w - 2) * 1152);
    float* po = outp + (SPLIT ? (size_t)half * B_N * D_N : 0);
    #pragma unroll
    for (int ct = 0; ct < 2; ++ct) {
      __syncthreads();
      #pragma unroll
      for (int q = 0; q < 4; ++q) {
        f32x4 v;
        #pragma unroll
        for (int i = 0; i < 4; ++i)
          v[i] = ct ? oa1[q * 4 + i] : oa0[q * 4 + i];
        *(f32x4*)(tb + l31 * 36 + q * 8 + hi * 4) = v;   // [brow][dcol-in-tile]
      }
      __syncthreads();
      #pragma unroll
      for (int p = 0; p < 2; ++p) {
        int row = (l >> 2) + p * 16;
        f32x4 v0 = *(const f32x4*)(tb + row * 36 + (l & 3) * 8);
        f32x4 v1 = *(const f32x4*)(tb + row * 36 + (l & 3) * 8 + 4);
        float* op = po + (size_t)(b0 + row) * D_N + w * 64 + ct * 32 + (l & 3) * 8;
        *(f32x4*)op = v0;
        *(f32x4*)(op + 4) = v1;
      }
    }
  }
  if (SPLIT && tid < BT) pwsum[half * B_N + b0 + tid] = wsum_lds[tid];
}

// ---------------- combine (SPLIT path) ----------------
__global__ __launch_bounds__(256)
void lsi_combine(const float* __restrict__ pout, const float* __restrict__ pwsum,
                 float* __restrict__ out)
{
  size_t i4 = ((size_t)blockIdx.x * 256 + threadIdx.x) * 4;
  int row = (int)(i4 >> 8);   // D_N = 256
  f32x4 a = *(const f32x4*)(pout + i4);
  f32x4 b = *(const f32x4*)(pout + (size_t)B_N * D_N + i4);
  float ws = pwsum[row] + pwsum[B_N + row];
  float inv = 1.f / (ws + 1e-6f);
  f32x4 r;
  #pragma unroll
  for (int i = 0; i < 4; ++i) r[i] = (a[i] + b[i]) * inv;
  *(f32x4*)(out + i4) = r;
}

extern "C" void kernel_launch(void* const* d_in, const int* in_sizes, int n_in,
                              void* d_out, int out_size, void* d_ws, size_t ws_size,
                              hipStream_t stream) {
  const float* x   = (const float*)d_in[0];
  const float* W1  = (const float*)d_in[1];
  const float* b1  = (const float*)d_in[2];
  const float* W2  = (const float*)d_in[3];
  const float* b2  = (const float*)d_in[4];
  const float* Wc1 = (const float*)d_in[5];
  const float* bc1 = (const float*)d_in[6];
  const float* Wc2 = (const float*)d_in[7];
  const float* bc2 = (const float*)d_in[8];
  const float* lam = (const float*)d_in[9];
  float* out = (float*)d_out;

  // ws: W1t 1MB | W2t 1MB | Wft 128KB | bcf 2KB | pwsum 128KB | pout 32MB
  unsigned short* W1t = (unsigned short*)d_ws;
  unsigned short* W2t = W1t + (size_t)S_N * H_N * D_N;
  unsigned short* Wft = W2t + (size_t)S_N * D_N * H_N;
  float* bcf   = (float*)(Wft + (size_t)S_N * K_N * H_N);
  float* pwsum = bcf + S_N * K_N;
  float* pout  = pwsum + 2 * B_N;
  size_t need = (size_t)((char*)(pout + (size_t)2 * B_N * D_N) - (char*)d_ws);

  lsi_prep<<<dim3(1152), dim3(256), 0, stream>>>(W1, W2, Wc1, b2, bc1,
                                                 W1t, W2t, Wft, bcf);
  if (ws_size >= need) {
    lsi_main<1><<<dim3(1024), dim3(256), 0, stream>>>(x, b1, b2, Wc2, bc2, lam,
                                                      W1t, W2t, Wft, bcf, pout, pwsum);
    lsi_combine<<<dim3((B_N * D_N) / 1024), dim3(256), 0, stream>>>(pout, pwsum, out);
  } else {
    lsi_main<0><<<dim3(512), dim3(256), 0, stream>>>(x, b1, b2, Wc2, bc2, lam,
                                                     W1t, W2t, Wft, bcf, out, nullptr);
  }
}

// Round 14
// 168.653 us; speedup vs baseline: 1.0755x; 1.0755x over previous
//
#include <hip/hip_runtime.h>
#include <math.h>

// Problem constants
#define S_N 16
#define D_N 256
#define H_N 128
#define K_N 32
#define BT  32
#define B_N 16384

typedef __attribute__((ext_vector_type(8))) short bf16x8;
typedef __attribute__((ext_vector_type(4))) short bf16x4;
typedef __attribute__((ext_vector_type(4))) float f32x4;
typedef __attribute__((ext_vector_type(16))) float f32x16;

#define MFMA32(a, b, c) __builtin_amdgcn_mfma_f32_32x32x16_bf16(a, b, c, 0, 0, 0)
#define SWZ(r) ((unsigned)(((r) & 15) << 4))

static __device__ __forceinline__ unsigned short f2bf(float f) {
  union { float f; unsigned u; } v; v.f = f;
  unsigned r = v.u + 0x7FFFu + ((v.u >> 16) & 1u);  // RNE
  return (unsigned short)(r >> 16);
}

// ---------------- merged pre-pass (unchanged) ----------------
__global__ __launch_bounds__(256)
void lsi_prep(const float* __restrict__ W1, const float* __restrict__ W2,
              const float* __restrict__ Wc1, const float* __restrict__ b2,
              const float* __restrict__ bc1,
              unsigned short* __restrict__ W1t,
              unsigned short* __restrict__ W2t,
              unsigned short* __restrict__ Wft,
              float* __restrict__ bcf)
{
  const int bid = blockIdx.x;
  if (bid < 1024) {
    __shared__ float t[32][33];
    const float* src; unsigned short* dst; int R, C, r0, c0;
    if (bid < 512) {
      int s = bid >> 5, tt = bid & 31;
      R = 256; C = 128; r0 = (tt >> 2) * 32; c0 = (tt & 3) * 32;
      src = W1 + (size_t)s * 256 * 128; dst = W1t + (size_t)s * 128 * 256;
    } else {
      int s = (bid - 512) >> 5, tt = (bid - 512) & 31;
      R = 128; C = 256; r0 = (tt >> 3) * 32; c0 = (tt & 7) * 32;
      src = W2 + (size_t)s * 128 * 256; dst = W2t + (size_t)s * 256 * 128;
    }
    int li = threadIdx.x >> 5, lj = threadIdx.x & 31;
    #pragma unroll
    for (int i = 0; i < 4; ++i)
      t[li + i * 8][lj] = src[(size_t)(r0 + li + i * 8) * C + c0 + lj];
    __syncthreads();
    #pragma unroll
    for (int i = 0; i < 4; ++i)
      dst[(size_t)(c0 + li + i * 8) * R + r0 + lj] = f2bf(t[lj][li + i * 8]);
    return;
  }
  const int q  = bid - 1024;
  const int s  = q >> 3, hb = q & 7;
  const int t  = threadIdx.x;
  const int hh = hb * 16 + (t >> 4);
  const int kb = (t & 15) * 2;
  const float* w2r = W2 + ((size_t)s * H_N + hh) * D_N;
  const float* wc1 = Wc1 + (size_t)s * D_N * K_N;
  float a0 = 0.f, a1 = 0.f;
  for (int d = 0; d < D_N; ++d) {
    float wv = w2r[d];
    a0 = fmaf(wv, wc1[d * K_N + kb], a0);
    a1 = fmaf(wv, wc1[d * K_N + kb + 1], a1);
  }
  Wft[((size_t)s * K_N + kb) * H_N + hh]     = f2bf(a0);
  Wft[((size_t)s * K_N + kb + 1) * H_N + hh] = f2bf(a1);
  if (hb == 0 && t < K_N) {
    float a = bc1[s * K_N + t];
    for (int d = 0; d < D_N; ++d)
      a = fmaf(b2[s * D_N + d], wc1[d * K_N + t], a);
    bcf[s * K_N + t] = a;
  }
}

// ---------------- fused main kernel: wave-private source pipeline ----------------
// grid 512 (BT=32 rows/block), block 512 (8 waves), 146 KB LDS, 3 barriers TOTAL.
// Phase A (no inter-wave deps): wave w owns sources {2w, 2w+1} end-to-end:
//   GEMM1 transposed C[hcol][brow] (4 indep MFMA32 chains, K=256) -> h unscaled;
//   conf in-wave: C[k][brow] (8 MFMA32) -> z via VALU + 1 shfl -> cv;
//   rewrite h scaled by cv from registers (acc2 eliminated algebraically:
//   sum_s cw.(h.W2) = sum_s (cw.h).W2 — numerics validated in R13).
// barrier. Phase C: GEMM2 streams ALL 16 sources into out_acc (2 indep chains,
// 128 MFMA32, 256 indep 16B loads — deep pipelinable stream, no barriers).
// Epilogue: wsum/bias-fold from cwh history, normalize, LDS-transpose store.
__global__ __launch_bounds__(512, 2)
void lsi_main(const float* __restrict__ x,
              const float* __restrict__ b1,
              const float* __restrict__ b2,
              const float* __restrict__ Wc2,
              const float* __restrict__ bc2,
              const float* __restrict__ lam,
              const unsigned short* __restrict__ W1t,
              const unsigned short* __restrict__ W2t,
              const unsigned short* __restrict__ Wft,
              const float* __restrict__ bcf,
              float* __restrict__ out)
{
  __shared__ __align__(16) unsigned short x_lds[BT * D_N];        // 16 KB
  __shared__ __align__(16) unsigned short h_lds[S_N][BT * H_N];   // 128 KB
  __shared__ float cwh[S_N][BT];                                  // 2 KB

  const int tid = threadIdx.x;
  const int w   = tid >> 6;       // wave 0..7
  const int l   = tid & 63;
  const int l31 = l & 31;
  const int hi  = l >> 5;
  const int b0  = blockIdx.x * BT;

  // ---- stage x tile [32 x 256] -> bf16 LDS (swizzled [brow][k]) ----
  {
    int row = tid >> 4;                 // 0..31 (16 threads/row)
    int c0  = (tid & 15) * 16;          // 16 f32 per thread
    const float* xr = x + (size_t)(b0 + row) * D_N + c0;
    #pragma unroll
    for (int cc = 0; cc < 2; ++cc) {
      float4 f0 = *(const float4*)(xr + cc * 8);
      float4 f1 = *(const float4*)(xr + cc * 8 + 4);
      bf16x8 u;
      u[0] = f2bf(f0.x); u[1] = f2bf(f0.y); u[2] = f2bf(f0.z); u[3] = f2bf(f0.w);
      u[4] = f2bf(f1.x); u[5] = f2bf(f1.y); u[6] = f2bf(f1.z); u[7] = f2bf(f1.w);
      unsigned off = (unsigned)(row * 512 + (c0 + cc * 8) * 2) ^ SWZ(row);
      *(bf16x8*)((char*)x_lds + off) = u;
    }
  }
  __syncthreads();   // BAR 1: x staged

  // ================= Phase A: wave-private, barrier-free =================
  #pragma unroll
  for (int j = 0; j < 2; ++j) {
    const int s = 2 * w + j;
    unsigned short* hs = h_lds[s];

    // ---- GEMM1: C[hcol][brow]; 4 independent chains; K=256 ----
    f32x16 a[4];
    #pragma unroll
    for (int t = 0; t < 4; ++t)
      #pragma unroll
      for (int i = 0; i < 16; ++i) a[t][i] = 0.f;
    const unsigned short* A1 = W1t + (size_t)s * H_N * D_N + (size_t)l31 * D_N + hi * 8;
    #pragma unroll
    for (int kf = 0; kf < 16; ++kf) {
      bf16x8 bx = *(const bf16x8*)((const char*)x_lds +
                    ((unsigned)(l31 * 512 + kf * 32 + hi * 16) ^ SWZ(l31)));
      a[0] = MFMA32(*(const bf16x8*)(A1 + kf * 16),              bx, a[0]);
      a[1] = MFMA32(*(const bf16x8*)(A1 + 32 * D_N + kf * 16),   bx, a[1]);
      a[2] = MFMA32(*(const bf16x8*)(A1 + 64 * D_N + kf * 16),   bx, a[2]);
      a[3] = MFMA32(*(const bf16x8*)(A1 + 96 * D_N + kf * 16),   bx, a[3]);
    }
    // a := relu(a + b1) (keep f32 in regs); write unscaled bf16 h for conf
    #pragma unroll
    for (int t = 0; t < 4; ++t)
      #pragma unroll
      for (int q = 0; q < 4; ++q) {
        f32x4 b4 = *(const f32x4*)(b1 + s * H_N + t * 32 + q * 8 + hi * 4);
        bf16x4 hv;
        #pragma unroll
        for (int i = 0; i < 4; ++i) {
          float v = fmaxf(a[t][q * 4 + i] + b4[i], 0.f);
          a[t][q * 4 + i] = v;
          hv[i] = (short)f2bf(v);
        }
        unsigned off = (unsigned)(l31 * 256 + (t * 32 + q * 8 + hi * 4) * 2) ^ SWZ(l31);
        *(bf16x4*)((char*)hs + off) = hv;
      }

    // ---- conf: C[k][brow]; A=Wft, B=h; K=128 -> 8 MFMA32 ----
    f32x16 c3;
    #pragma unroll
    for (int i = 0; i < 16; ++i) c3[i] = 0.f;
    const unsigned short* Af = Wft + (size_t)s * K_N * H_N + (size_t)l31 * H_N + hi * 8;
    #pragma unroll
    for (int kf = 0; kf < 8; ++kf) {
      bf16x8 hb = *(const bf16x8*)((const char*)hs +
                    ((unsigned)(l31 * 256 + kf * 32 + hi * 16) ^ SWZ(l31)));
      c3 = MFMA32(*(const bf16x8*)(Af + kf * 16), hb, c3);
    }
    float zz = 0.f;
    #pragma unroll
    for (int q = 0; q < 4; ++q) {
      f32x4 bc4 = *(const f32x4*)(bcf + s * K_N + q * 8 + hi * 4);
      f32x4 wc4 = *(const f32x4*)(Wc2 + s * K_N + q * 8 + hi * 4);
      #pragma unroll
      for (int i = 0; i < 4; ++i)
        zz += fmaxf(c3[q * 4 + i] + bc4[i], 0.f) * wc4[i];
    }
    zz += __shfl_xor(zz, 32);          // combine hi/lo k-halves: full sum in all lanes
    const float cv = lam[s] / (1.f + __expf(-(zz + bc2[s])));
    if (hi == 0) cwh[s][l31] = cv;     // history for epilogue (brow = l31)

    // ---- rewrite h scaled by cv, straight from registers ----
    #pragma unroll
    for (int t = 0; t < 4; ++t)
      #pragma unroll
      for (int q = 0; q < 4; ++q) {
        bf16x4 hv;
        #pragma unroll
        for (int i = 0; i < 4; ++i)
          hv[i] = (short)f2bf(a[t][q * 4 + i] * cv);
        unsigned off = (unsigned)(l31 * 256 + (t * 32 + q * 8 + hi * 4) * 2) ^ SWZ(l31);
        *(bf16x4*)((char*)hs + off) = hv;
      }
  }
  __syncthreads();   // BAR 2: all 16 scaled h tiles ready

  // ================= Phase C: GEMM2 stream over all sources =================
  // C[dcol][brow]; wave w -> dcols [32w,32w+32); 2 independent chains (even/odd kf)
  f32x16 oa, ob;
  #pragma unroll
  for (int i = 0; i < 16; ++i) { oa[i] = 0.f; ob[i] = 0.f; }
  for (int s = 0; s < S_N; ++s) {
    const unsigned short* A2 = W2t + (size_t)s * D_N * H_N +
                               (size_t)(w * 32 + l31) * H_N + hi * 8;
    const unsigned short* hs = h_lds[s];
    #pragma unroll
    for (int kf = 0; kf < 8; kf += 2) {
      bf16x8 hb0 = *(const bf16x8*)((const char*)hs +
                     ((unsigned)(l31 * 256 + kf * 32 + hi * 16) ^ SWZ(l31)));
      bf16x8 hb1 = *(const bf16x8*)((const char*)hs +
                     ((unsigned)(l31 * 256 + (kf + 1) * 32 + hi * 16) ^ SWZ(l31)));
      oa = MFMA32(*(const bf16x8*)(A2 + kf * 16),       hb0, oa);
      ob = MFMA32(*(const bf16x8*)(A2 + (kf + 1) * 16), hb1, ob);
    }
  }

  // ---- epilogue: wsum, bias fold (sum_s cw_s[brow] * b2_s[dcol]), normalize ----
  float ws = 0.f;
  #pragma unroll
  for (int s = 0; s < S_N; ++s) ws += cwh[s][l31];
  const float winv = 1.f / (ws + 1e-6f);
  #pragma unroll
  for (int q = 0; q < 4; ++q) {
    const int dc = w * 32 + q * 8 + hi * 4;
    f32x4 acc;
    #pragma unroll
    for (int i = 0; i < 4; ++i) acc[i] = oa[q * 4 + i] + ob[q * 4 + i];
    for (int s = 0; s < S_N; ++s) {
      const float c = cwh[s][l31];
      f32x4 b4 = *(const f32x4*)(b2 + s * D_N + dc);
      #pragma unroll
      for (int i = 0; i < 4; ++i) acc[i] += c * b4[i];
    }
    #pragma unroll
    for (int i = 0; i < 4; ++i) oa[q * 4 + i] = acc[i] * winv;
  }
  __syncthreads();   // BAR 3: h_lds free for transpose buffers

  // ---- per-wave LDS transpose -> coalesced f32x4 stores ----
  {
    float* tb = (float*)h_lds + (size_t)w * 1152;   // 32 rows x 36 f32
    #pragma unroll
    for (int q = 0; q < 4; ++q)
      *(f32x4*)(tb + l31 * 36 + q * 8 + hi * 4) =
        (f32x4){oa[q * 4 + 0], oa[q * 4 + 1], oa[q * 4 + 2], oa[q * 4 + 3]};
    // same-wave ds write->read: program order, no barrier needed
    #pragma unroll
    for (int p = 0; p < 2; ++p) {
      int row = (l >> 2) + p * 16;
      f32x4 v0 = *(const f32x4*)(tb + row * 36 + (l & 3) * 8);
      f32x4 v1 = *(const f32x4*)(tb + row * 36 + (l & 3) * 8 + 4);
      float* op = out + (size_t)(b0 + row) * D_N + w * 32 + (l & 3) * 8;
      *(f32x4*)op = v0;
      *(f32x4*)(op + 4) = v1;
    }
  }
}

extern "C" void kernel_launch(void* const* d_in, const int* in_sizes, int n_in,
                              void* d_out, int out_size, void* d_ws, size_t ws_size,
                              hipStream_t stream) {
  const float* x   = (const float*)d_in[0];
  const float* W1  = (const float*)d_in[1];
  const float* b1  = (const float*)d_in[2];
  const float* W2  = (const float*)d_in[3];
  const float* b2  = (const float*)d_in[4];
  const float* Wc1 = (const float*)d_in[5];
  const float* bc1 = (const float*)d_in[6];
  const float* Wc2 = (const float*)d_in[7];
  const float* bc2 = (const float*)d_in[8];
  const float* lam = (const float*)d_in[9];
  float* out = (float*)d_out;

  // ws: W1t 1MB | W2t 1MB | Wft 128KB | bcf 2KB
  unsigned short* W1t = (unsigned short*)d_ws;
  unsigned short* W2t = W1t + (size_t)S_N * H_N * D_N;
  unsigned short* Wft = W2t + (size_t)S_N * D_N * H_N;
  float* bcf = (float*)(Wft + (size_t)S_N * K_N * H_N);

  lsi_prep<<<dim3(1152), dim3(256), 0, stream>>>(W1, W2, Wc1, b2, bc1,
                                                 W1t, W2t, Wft, bcf);
  lsi_main<<<dim3(B_N / BT), dim3(512), 0, stream>>>(x, b1, b2, Wc2, bc2, lam,
                                                     W1t, W2t, Wft, bcf, out);
}

// Round 15
// 146.618 us; speedup vs baseline: 1.2372x; 1.1503x over previous
//
#include <hip/hip_runtime.h>
#include <math.h>

// Problem constants
#define S_N 16
#define D_N 256
#define H_N 128
#define K_N 32
#define BT  64
#define B_N 16384

typedef __attribute__((ext_vector_type(8))) short bf16x8;
typedef __attribute__((ext_vector_type(4))) float f32x4;

#define MFMA16(a, b, c) __builtin_amdgcn_mfma_f32_16x16x32_bf16(a, b, c, 0, 0, 0)
#define SWZ8(r) ((unsigned)(((r) & 7) << 4))

static __device__ __forceinline__ unsigned short f2bf(float f) {
  union { float f; unsigned u; } v; v.f = f;
  unsigned r = v.u + 0x7FFFu + ((v.u >> 16) & 1u);  // RNE
  return (unsigned short)(r >> 16);
}

// ---------------- merged pre-pass (R9, unchanged) ----------------
__global__ __launch_bounds__(256)
void lsi_prep(const float* __restrict__ W1, const float* __restrict__ W2,
              const float* __restrict__ Wc1, const float* __restrict__ b2,
              const float* __restrict__ bc1,
              unsigned short* __restrict__ W1t,
              unsigned short* __restrict__ W2t,
              unsigned short* __restrict__ Wft,
              float* __restrict__ bcf)
{
  const int bid = blockIdx.x;
  if (bid < 1024) {
    __shared__ float t[32][33];
    const float* src; unsigned short* dst; int R, C, r0, c0;
    if (bid < 512) {
      int s = bid >> 5, tt = bid & 31;
      R = 256; C = 128; r0 = (tt >> 2) * 32; c0 = (tt & 3) * 32;
      src = W1 + (size_t)s * 256 * 128; dst = W1t + (size_t)s * 128 * 256;
    } else {
      int s = (bid - 512) >> 5, tt = (bid - 512) & 31;
      R = 128; C = 256; r0 = (tt >> 3) * 32; c0 = (tt & 7) * 32;
      src = W2 + (size_t)s * 128 * 256; dst = W2t + (size_t)s * 256 * 128;
    }
    int li = threadIdx.x >> 5, lj = threadIdx.x & 31;
    #pragma unroll
    for (int i = 0; i < 4; ++i)
      t[li + i * 8][lj] = src[(size_t)(r0 + li + i * 8) * C + c0 + lj];
    __syncthreads();
    #pragma unroll
    for (int i = 0; i < 4; ++i)
      dst[(size_t)(c0 + li + i * 8) * R + r0 + lj] = f2bf(t[lj][li + i * 8]);
    return;
  }
  const int q  = bid - 1024;
  const int s  = q >> 3, hb = q & 7;
  const int t  = threadIdx.x;
  const int hh = hb * 16 + (t >> 4);
  const int kb = (t & 15) * 2;
  const float* w2r = W2 + ((size_t)s * H_N + hh) * D_N;
  const float* wc1 = Wc1 + (size_t)s * D_N * K_N;
  float a0 = 0.f, a1 = 0.f;
  for (int d = 0; d < D_N; ++d) {
    float wv = w2r[d];
    a0 = fmaf(wv, wc1[d * K_N + kb], a0);
    a1 = fmaf(wv, wc1[d * K_N + kb + 1], a1);
  }
  Wft[((size_t)s * K_N + kb) * H_N + hh]     = f2bf(a0);
  Wft[((size_t)s * K_N + kb + 1) * H_N + hh] = f2bf(a1);
  if (hb == 0 && t < K_N) {
    float a = bc1[s * K_N + t];
    for (int d = 0; d < D_N; ++d)
      a = fmaf(b2[s * D_N + d], wc1[d * K_N + t], a);
    bcf[s * K_N + t] = a;
  }
}

// ---------------- fused main kernel: R9 schedule at 16 waves ----------------
// grid 256 (BT=64), block 1024 (16 waves -> FORCED 4 waves/SIMD residency).
// Same work split as R9 spread over 2x waves (half accumulator state/wave):
//   GEMM1: wave w -> h-coltile (w&7), row-half (w>>3); acc1[2]
//   conf : waves 0-3 (rowtile w, both k-tiles), in-wave shfl; as R9
//   GEMM2: wave w -> d-coltile w (16 cols), all 4 rowtiles; acc2[4]
//   fold : out_acc[4] += cw * acc2 (prev source)
// 1 barrier/source, double-buffered h, x staged once. LDS ~65 KB.
__global__ __launch_bounds__(1024)
void lsi_main(const float* __restrict__ x,
              const float* __restrict__ b1,
              const float* __restrict__ b2,
              const float* __restrict__ Wc2,
              const float* __restrict__ bc2,
              const float* __restrict__ lam,
              const unsigned short* __restrict__ W1t,
              const unsigned short* __restrict__ W2t,
              const unsigned short* __restrict__ Wft,
              const float* __restrict__ bcf,
              float* __restrict__ out)
{
  __shared__ __align__(16) unsigned short x_lds[BT * D_N];      // 32 KB
  __shared__ __align__(16) unsigned short h_lds[2][BT * H_N];   // 32 KB
  __shared__ float cw_lds[2][BT];
  __shared__ float wsum_lds[BT];

  const int tid = threadIdx.x;
  const int w   = tid >> 6;       // wave 0..15
  const int l   = tid & 63;
  const int rA  = l & 15;
  const int g   = l >> 4;         // 0..3
  const int k8  = g * 8;
  const int b0  = blockIdx.x * BT;
  const int ct1 = w & 7;          // GEMM1 h-coltile
  const int rh  = w >> 3;         // GEMM1 row-half (0/1)

  // ---- stage x tile [64 x 256] -> bf16 LDS (swizzled) ----
  {
    int row = tid >> 4;                 // 0..63
    int c0  = (tid & 15) * 16;          // 16 f32 per thread
    const float* xr = x + (size_t)(b0 + row) * D_N + c0;
    #pragma unroll
    for (int cc = 0; cc < 2; ++cc) {
      float4 f0 = *(const float4*)(xr + cc * 8);
      float4 f1 = *(const float4*)(xr + cc * 8 + 4);
      bf16x8 u;
      u[0] = f2bf(f0.x); u[1] = f2bf(f0.y); u[2] = f2bf(f0.z); u[3] = f2bf(f0.w);
      u[4] = f2bf(f1.x); u[5] = f2bf(f1.y); u[6] = f2bf(f1.z); u[7] = f2bf(f1.w);
      unsigned off = (unsigned)(row * 512 + (c0 + cc * 8) * 2) ^ SWZ8(row);
      *(bf16x8*)((char*)x_lds + off) = u;
    }
  }
  if (tid < BT) wsum_lds[tid] = 0.f;

  f32x4 out_acc[4];   // d-coltile w, 4 rowtiles
  f32x4 acc2[4];
  #pragma unroll
  for (int rt = 0; rt < 4; ++rt)
    out_acc[rt] = (f32x4){0.f, 0.f, 0.f, 0.f};

  // GEMM1(s): wave -> coltile ct1, rows [rh*32, rh*32+32)
  auto do_gemm1 = [&](int s, unsigned short* hw) {
    f32x4 acc1[2];
    acc1[0] = (f32x4){0.f, 0.f, 0.f, 0.f};
    acc1[1] = (f32x4){0.f, 0.f, 0.f, 0.f};
    const unsigned short* B1 = W1t + ((size_t)s * H_N + ct1 * 16 + rA) * D_N + k8;
    #pragma unroll
    for (int ks = 0; ks < 8; ++ks) {
      bf16x8 bfr = *(const bf16x8*)(B1 + ks * 32);
      #pragma unroll
      for (int rt = 0; rt < 2; ++rt) {
        int row = rh * 32 + rt * 16 + rA;
        unsigned off = (unsigned)(row * 512 + (ks * 32 + k8) * 2) ^ SWZ8(row);
        bf16x8 afr = *(const bf16x8*)((const char*)x_lds + off);
        acc1[rt] = MFMA16(afr, bfr, acc1[rt]);
      }
    }
    const float b1v = b1[s * H_N + ct1 * 16 + rA];
    #pragma unroll
    for (int rt = 0; rt < 2; ++rt)
      #pragma unroll
      for (int i = 0; i < 4; ++i) {
        float v = fmaxf(acc1[rt][i] + b1v, 0.f);
        int row = rh * 32 + rt * 16 + g * 4 + i;
        unsigned off = (unsigned)(row * 256 + (ct1 * 16 + rA) * 2) ^ SWZ8(row);
        *(unsigned short*)((char*)hw + off) = f2bf(v);
      }
  };

  __syncthreads();             // x staged
  do_gemm1(0, h_lds[0]);
  __syncthreads();             // h(0) ready

  for (int s = 0; s < S_N; ++s) {
    const unsigned short* hr = (const unsigned short*)h_lds[s & 1];

    // ---- fold(s-1) ----
    if (s > 0) {
      #pragma unroll
      for (int rt = 0; rt < 4; ++rt) {
        f32x4 c4 = *(const f32x4*)&cw_lds[(s + 1) & 1][rt * 16 + g * 4];
        #pragma unroll
        for (int i = 0; i < 4; ++i)
          out_acc[rt][i] += c4[i] * acc2[rt][i];
      }
    }

    // ---- conf(s): waves 0-3; rowtile w, both k-tiles (as R9) ----
    if (w < 4) {
      f32x4 acc3[2];
      acc3[0] = (f32x4){0.f, 0.f, 0.f, 0.f};
      acc3[1] = (f32x4){0.f, 0.f, 0.f, 0.f};
      const unsigned short* Bf = Wft + ((size_t)s * K_N + rA) * H_N + k8;
      #pragma unroll
      for (int ks = 0; ks < 4; ++ks) {
        int row = w * 16 + rA;
        unsigned off = (unsigned)(row * 256 + (ks * 32 + k8) * 2) ^ SWZ8(row);
        bf16x8 afr = *(const bf16x8*)((const char*)hr + off);
        acc3[0] = MFMA16(afr, *(const bf16x8*)(Bf + ks * 32), acc3[0]);
        acc3[1] = MFMA16(afr, *(const bf16x8*)(Bf + 16 * H_N + ks * 32), acc3[1]);
      }
      const float bcf0 = bcf[s * K_N + rA],  bcf1 = bcf[s * K_N + 16 + rA];
      const float wc20 = Wc2[s * K_N + rA],  wc21 = Wc2[s * K_N + 16 + rA];
      float pz[4];
      #pragma unroll
      for (int i = 0; i < 4; ++i)
        pz[i] = fmaxf(acc3[0][i] + bcf0, 0.f) * wc20 +
                fmaxf(acc3[1][i] + bcf1, 0.f) * wc21;
      #pragma unroll
      for (int m = 1; m < 16; m <<= 1)
        #pragma unroll
        for (int i = 0; i < 4; ++i)
          pz[i] += __shfl_xor(pz[i], m);
      if (rA == 0) {
        const float lam_s = lam[s], bc2_s = bc2[s];
        #pragma unroll
        for (int i = 0; i < 4; ++i) {
          float cv = lam_s / (1.f + __expf(-(pz[i] + bc2_s)));
          cw_lds[s & 1][w * 16 + g * 4 + i] = cv;
          wsum_lds[w * 16 + g * 4 + i] += cv;
        }
      }
    }

    // ---- GEMM2(s): wave -> d-coltile w, all 4 rowtiles ----
    #pragma unroll
    for (int rt = 0; rt < 4; ++rt)
      acc2[rt] = (f32x4){0.f, 0.f, 0.f, 0.f};
    {
      const unsigned short* B2 = W2t + ((size_t)s * D_N + w * 16 + rA) * H_N + k8;
      #pragma unroll
      for (int ks = 0; ks < 4; ++ks) {
        bf16x8 bfr = *(const bf16x8*)(B2 + ks * 32);
        #pragma unroll
        for (int rt = 0; rt < 4; ++rt) {
          int row = rt * 16 + rA;
          unsigned off = (unsigned)(row * 256 + (ks * 32 + k8) * 2) ^ SWZ8(row);
          bf16x8 afr = *(const bf16x8*)((const char*)hr + off);
          acc2[rt] = MFMA16(afr, bfr, acc2[rt]);
        }
      }
      const float b2v = b2[s * D_N + w * 16 + rA];
      #pragma unroll
      for (int rt = 0; rt < 4; ++rt)
        #pragma unroll
        for (int i = 0; i < 4; ++i)
          acc2[rt][i] += b2v;
    }

    // ---- GEMM1(s+1) -> other h buffer ----
    if (s + 1 < S_N) do_gemm1(s + 1, h_lds[(s + 1) & 1]);

    __syncthreads();   // single barrier per source
  }

  // ---------- epilogue: fold s=15, normalize, store ----------
  #pragma unroll
  for (int rt = 0; rt < 4; ++rt) {
    f32x4 c4 = *(const f32x4*)&cw_lds[(S_N - 1) & 1][rt * 16 + g * 4];
    #pragma unroll
    for (int i = 0; i < 4; ++i)
      out_acc[rt][i] += c4[i] * acc2[rt][i];
  }
  #pragma unroll
  for (int rt = 0; rt < 4; ++rt) {
    f32x4 w4 = *(const f32x4*)&wsum_lds[rt * 16 + g * 4];
    #pragma unroll
    for (int i = 0; i < 4; ++i) {
      int row = rt * 16 + g * 4 + i;
      float winv = 1.f / (w4[i] + 1e-6f);
      out[(size_t)(b0 + row) * D_N + w * 16 + rA] = out_acc[rt][i] * winv;
    }
  }
}

extern "C" void kernel_launch(void* const* d_in, const int* in_sizes, int n_in,
                              void* d_out, int out_size, void* d_ws, size_t ws_size,
                              hipStream_t stream) {
  const float* x   = (const float*)d_in[0];
  const float* W1  = (const float*)d_in[1];
  const float* b1  = (const float*)d_in[2];
  const float* W2  = (const float*)d_in[3];
  const float* b2  = (const float*)d_in[4];
  const float* Wc1 = (const float*)d_in[5];
  const float* bc1 = (const float*)d_in[6];
  const float* Wc2 = (const float*)d_in[7];
  const float* bc2 = (const float*)d_in[8];
  const float* lam = (const float*)d_in[9];
  float* out = (float*)d_out;

  // ws: W1t 1MB | W2t 1MB | Wft 128KB | bcf 2KB
  unsigned short* W1t = (unsigned short*)d_ws;
  unsigned short* W2t = W1t + (size_t)S_N * H_N * D_N;
  unsigned short* Wft = W2t + (size_t)S_N * D_N * H_N;
  float* bcf = (float*)(Wft + (size_t)S_N * K_N * H_N);

  lsi_prep<<<dim3(1152), dim3(256), 0, stream>>>(W1, W2, Wc1, b2, bc1,
                                                 W1t, W2t, Wft, bcf);
  lsi_main<<<dim3(B_N / BT), dim3(1024), 0, stream>>>(x, b1, b2, Wc2, bc2, lam,
                                                      W1t, W2t, Wft, bcf, out);
}

// Round 16
// 124.159 us; speedup vs baseline: 1.4610x; 1.1809x over previous
//
#include <hip/hip_runtime.h>
#include <math.h>

// Problem constants
#define S_N 16
#define D_N 256
#define H_N 128
#define K_N 32
#define BT  64      // batch rows per workgroup
#define B_N 16384

typedef __attribute__((ext_vector_type(8))) short bf16x8;
typedef __attribute__((ext_vector_type(4))) float f32x4;

#define MFMA(a, b, c) __builtin_amdgcn_mfma_f32_16x16x32_bf16(a, b, c, 0, 0, 0)

static __device__ __forceinline__ unsigned short f2bf(float f) {
  union { float f; unsigned u; } v; v.f = f;
  unsigned r = v.u + 0x7FFFu + ((v.u >> 16) & 1u);  // RNE
  return (unsigned short)(r >> 16);
}

// ---------------- merged pre-pass (unchanged from R9) ----------------
__global__ __launch_bounds__(256)
void lsi_prep(const float* __restrict__ W1, const float* __restrict__ W2,
              const float* __restrict__ Wc1, const float* __restrict__ b2,
              const float* __restrict__ bc1,
              unsigned short* __restrict__ W1t,
              unsigned short* __restrict__ W2t,
              unsigned short* __restrict__ Wft,
              float* __restrict__ bcf)
{
  const int bid = blockIdx.x;
  if (bid < 1024) {
    __shared__ float t[32][33];
    const float* src; unsigned short* dst; int R, C, r0, c0;
    if (bid < 512) {
      int s = bid >> 5, tt = bid & 31;
      R = 256; C = 128; r0 = (tt >> 2) * 32; c0 = (tt & 3) * 32;
      src = W1 + (size_t)s * 256 * 128; dst = W1t + (size_t)s * 128 * 256;
    } else {
      int s = (bid - 512) >> 5, tt = (bid - 512) & 31;
      R = 128; C = 256; r0 = (tt >> 3) * 32; c0 = (tt & 7) * 32;
      src = W2 + (size_t)s * 128 * 256; dst = W2t + (size_t)s * 256 * 128;
    }
    int li = threadIdx.x >> 5, lj = threadIdx.x & 31;
    #pragma unroll
    for (int i = 0; i < 4; ++i)
      t[li + i * 8][lj] = src[(size_t)(r0 + li + i * 8) * C + c0 + lj];
    __syncthreads();
    #pragma unroll
    for (int i = 0; i < 4; ++i)
      dst[(size_t)(c0 + li + i * 8) * R + r0 + lj] = f2bf(t[lj][li + i * 8]);
    return;
  }
  const int q  = bid - 1024;
  const int s  = q >> 3, hb = q & 7;
  const int t  = threadIdx.x;
  const int hh = hb * 16 + (t >> 4);
  const int kb = (t & 15) * 2;
  const float* w2r = W2 + ((size_t)s * H_N + hh) * D_N;
  const float* wc1 = Wc1 + (size_t)s * D_N * K_N;
  float a0 = 0.f, a1 = 0.f;
  for (int d = 0; d < D_N; ++d) {
    float wv = w2r[d];
    a0 = fmaf(wv, wc1[d * K_N + kb], a0);
    a1 = fmaf(wv, wc1[d * K_N + kb + 1], a1);
  }
  Wft[((size_t)s * K_N + kb) * H_N + hh]     = f2bf(a0);
  Wft[((size_t)s * K_N + kb + 1) * H_N + hh] = f2bf(a1);
  if (hb == 0 && t < K_N) {
    float a = bc1[s * K_N + t];
    for (int d = 0; d < D_N; ++d)
      a = fmaf(b2[s * D_N + d], wc1[d * K_N + t], a);
    bcf[s * K_N + t] = a;
  }
}

// ---------------- fused main kernel (R9 structure, spill-free regalloc) ----
// grid = 256, block = 512 (8 waves), 1 block/CU. One barrier per source,
// double-buffered h. R9 @ (512,2) spilled ~9 dwords/thread (WRITE 21MB vs
// 16.4 ideal): the 128-VGPR cap is just under the ~150-reg true demand.
// (512,1) lifts the cap to 256; occupancy stays 2 waves/SIMD (state <256),
// which R3/R13/R15 showed is not the binding resource. Single-variable fix.
__global__ __launch_bounds__(512, 1)
void lsi_main(const float* __restrict__ x,
              const float* __restrict__ b1,
              const float* __restrict__ b2,
              const float* __restrict__ Wc2,
              const float* __restrict__ bc2,
              const float* __restrict__ lam,
              const unsigned short* __restrict__ W1t,
              const unsigned short* __restrict__ W2t,
              const unsigned short* __restrict__ Wft,
              const float* __restrict__ bcf,
              float* __restrict__ out)
{
  __shared__ unsigned short x_lds[BT * D_N];      // 32 KB, swizzled
  __shared__ unsigned short h_lds[2][BT * H_N];   // 2 x 16 KB, swizzled
  __shared__ float cw_lds[2][BT];
  __shared__ float wsum_lds[BT];

  const int tid = threadIdx.x;
  const int w   = tid >> 6;       // wave 0..7
  const int l   = tid & 63;       // lane
  const int rA  = l & 15;
  const int g   = l >> 4;         // 0..3
  const int k8  = g * 8;
  const int b0  = blockIdx.x * BT;

  // ---- stage x tile into LDS as bf16 (swizzled) ----
  {
    int row = tid >> 3;                 // 0..63
    int c0  = (tid & 7) * 32;           // 8 threads per row
    const float* xr = x + (size_t)(b0 + row) * D_N + c0;
    #pragma unroll
    for (int cc = 0; cc < 4; ++cc) {
      float4 f0 = *(const float4*)(xr + cc * 8);
      float4 f1 = *(const float4*)(xr + cc * 8 + 4);
      bf16x8 u;
      u[0] = f2bf(f0.x); u[1] = f2bf(f0.y); u[2] = f2bf(f0.z); u[3] = f2bf(f0.w);
      u[4] = f2bf(f1.x); u[5] = f2bf(f1.y); u[6] = f2bf(f1.z); u[7] = f2bf(f1.w);
      unsigned off = (unsigned)(row * 512 + (c0 + cc * 8) * 2) ^ (unsigned)((row & 7) << 4);
      *(bf16x8*)((char*)x_lds + off) = u;
    }
  }
  if (tid < BT) wsum_lds[tid] = 0.f;

  f32x4 out_acc[2][4];   // [ct][rt] persistent
  f32x4 acc2[2][4];      // [ct][rt] outs(s), folded one source later
  #pragma unroll
  for (int a = 0; a < 2; ++a)
    #pragma unroll
    for (int b = 0; b < 4; ++b)
      out_acc[a][b] = (f32x4){0.f, 0.f, 0.f, 0.f};

  // GEMM1 for source s -> given h buffer (col-split: wave w -> cols 16w..16w+16)
  auto do_gemm1 = [&](int s, unsigned short* hw) {
    f32x4 acc1[4];
    #pragma unroll
    for (int rt = 0; rt < 4; ++rt) acc1[rt] = (f32x4){0.f, 0.f, 0.f, 0.f};
    const unsigned short* B1 = W1t + ((size_t)s * H_N + w * 16 + rA) * D_N + k8;
    #pragma unroll
    for (int ks = 0; ks < 8; ++ks) {
      bf16x8 bfr = *(const bf16x8*)(B1 + ks * 32);
      #pragma unroll
      for (int rt = 0; rt < 4; ++rt) {
        int row = rt * 16 + rA;
        unsigned off = (unsigned)(row * 512 + (ks * 32 + k8) * 2) ^ (unsigned)((row & 7) << 4);
        bf16x8 afr = *(const bf16x8*)((const char*)x_lds + off);
        acc1[rt] = MFMA(afr, bfr, acc1[rt]);
      }
    }
    const float b1v = b1[s * H_N + w * 16 + rA];
    #pragma unroll
    for (int rt = 0; rt < 4; ++rt)
      #pragma unroll
      for (int i = 0; i < 4; ++i) {
        float v = fmaxf(acc1[rt][i] + b1v, 0.f);
        int row = rt * 16 + g * 4 + i;
        unsigned off = (unsigned)(row * 256 + (w * 16 + rA) * 2) ^ (unsigned)((row & 7) << 4);
        *(unsigned short*)((char*)hw + off) = f2bf(v);
      }
  };

  __syncthreads();             // x staged
  do_gemm1(0, h_lds[0]);       // prologue
  __syncthreads();             // h(0) ready

  for (int s = 0; s < S_N; ++s) {
    const unsigned short* hr = (const unsigned short*)h_lds[s & 1];

    // ---- fold(s-1): VALU, overlaps MFMA phases of other waves ----
    if (s > 0) {
      #pragma unroll
      for (int rt = 0; rt < 4; ++rt) {
        f32x4 c4 = *(const f32x4*)&cw_lds[(s + 1) & 1][rt * 16 + g * 4];
        #pragma unroll
        for (int i = 0; i < 4; ++i) {
          out_acc[0][rt][i] += c4[i] * acc2[0][rt][i];
          out_acc[1][rt][i] += c4[i] * acc2[1][rt][i];
        }
      }
    }

    // ---- conf(s): waves 0-3 only; wave w -> rows [16w,16w+16), all 32 k ----
    if (w < 4) {
      f32x4 acc3[2];
      acc3[0] = (f32x4){0.f, 0.f, 0.f, 0.f};
      acc3[1] = (f32x4){0.f, 0.f, 0.f, 0.f};
      const unsigned short* Bf = Wft + ((size_t)s * K_N + rA) * H_N + k8;
      #pragma unroll
      for (int ks = 0; ks < 4; ++ks) {
        int row = w * 16 + rA;
        unsigned off = (unsigned)(row * 256 + (ks * 32 + k8) * 2) ^ (unsigned)((row & 7) << 4);
        bf16x8 afr = *(const bf16x8*)((const char*)hr + off);
        acc3[0] = MFMA(afr, *(const bf16x8*)(Bf + ks * 32), acc3[0]);
        acc3[1] = MFMA(afr, *(const bf16x8*)(Bf + 16 * H_N + ks * 32), acc3[1]);
      }
      const float bcf0 = bcf[s * K_N + rA],  bcf1 = bcf[s * K_N + 16 + rA];
      const float wc20 = Wc2[s * K_N + rA],  wc21 = Wc2[s * K_N + 16 + rA];
      float pz[4];
      #pragma unroll
      for (int i = 0; i < 4; ++i)
        pz[i] = fmaxf(acc3[0][i] + bcf0, 0.f) * wc20 +
                fmaxf(acc3[1][i] + bcf1, 0.f) * wc21;
      #pragma unroll
      for (int m = 1; m < 16; m <<= 1)
        #pragma unroll
        for (int i = 0; i < 4; ++i)
          pz[i] += __shfl_xor(pz[i], m);
      if (rA == 0) {
        const float lam_s = lam[s], bc2_s = bc2[s];
        #pragma unroll
        for (int i = 0; i < 4; ++i) {
          float cv = lam_s / (1.f + __expf(-(pz[i] + bc2_s)));
          cw_lds[s & 1][w * 16 + g * 4 + i] = cv;
          wsum_lds[w * 16 + g * 4 + i] += cv;
        }
      }
    }

    // ---- GEMM2(s) -> acc2 (all waves; wave w -> d-cols [32w,32w+32)) ----
    #pragma unroll
    for (int a = 0; a < 2; ++a)
      #pragma unroll
      for (int b = 0; b < 4; ++b)
        acc2[a][b] = (f32x4){0.f, 0.f, 0.f, 0.f};
    {
      const unsigned short* B2 = W2t + ((size_t)s * D_N + w * 32 + rA) * H_N + k8;
      #pragma unroll
      for (int ks = 0; ks < 4; ++ks) {
        bf16x8 afr[4];
        #pragma unroll
        for (int rt = 0; rt < 4; ++rt) {
          int row = rt * 16 + rA;
          unsigned off = (unsigned)(row * 256 + (ks * 32 + k8) * 2) ^ (unsigned)((row & 7) << 4);
          afr[rt] = *(const bf16x8*)((const char*)hr + off);
        }
        #pragma unroll
        for (int ct = 0; ct < 2; ++ct) {
          bf16x8 bfr = *(const bf16x8*)(B2 + ct * 16 * H_N + ks * 32);
          #pragma unroll
          for (int rt = 0; rt < 4; ++rt)
            acc2[ct][rt] = MFMA(afr[rt], bfr, acc2[ct][rt]);
        }
      }
      float b2v0 = b2[s * D_N + w * 32 + rA];
      float b2v1 = b2[s * D_N + w * 32 + 16 + rA];
      #pragma unroll
      for (int rt = 0; rt < 4; ++rt)
        #pragma unroll
        for (int i = 0; i < 4; ++i) {
          acc2[0][rt][i] += b2v0;
          acc2[1][rt][i] += b2v1;
        }
    }

    // ---- GEMM1(s+1) -> other h buffer ----
    if (s + 1 < S_N) do_gemm1(s + 1, h_lds[(s + 1) & 1]);

    __syncthreads();   // single barrier per source
  }

  // ---------- epilogue: fold s=15, normalize, store ----------
  #pragma unroll
  for (int rt = 0; rt < 4; ++rt) {
    f32x4 c4 = *(const f32x4*)&cw_lds[(S_N - 1) & 1][rt * 16 + g * 4];
    #pragma unroll
    for (int i = 0; i < 4; ++i) {
      out_acc[0][rt][i] += c4[i] * acc2[0][rt][i];
      out_acc[1][rt][i] += c4[i] * acc2[1][rt][i];
    }
  }
  #pragma unroll
  for (int rt = 0; rt < 4; ++rt) {
    f32x4 w4 = *(const f32x4*)&wsum_lds[rt * 16 + g * 4];
    #pragma unroll
    for (int i = 0; i < 4; ++i) {
      int row = rt * 16 + g * 4 + i;
      float winv = 1.f / (w4[i] + 1e-6f);
      out[(size_t)(b0 + row) * D_N + w * 32 + rA]      = out_acc[0][rt][i] * winv;
      out[(size_t)(b0 + row) * D_N + w * 32 + 16 + rA] = out_acc[1][rt][i] * winv;
    }
  }
}

extern "C" void kernel_launch(void* const* d_in, const int* in_sizes, int n_in,
                              void* d_out, int out_size, void* d_ws, size_t ws_size,
                              hipStream_t stream) {
  const float* x   = (const float*)d_in[0];
  const float* W1  = (const float*)d_in[1];
  const float* b1  = (const float*)d_in[2];
  const float* W2  = (const float*)d_in[3];
  const float* b2  = (const float*)d_in[4];
  const float* Wc1 = (const float*)d_in[5];
  const float* bc1 = (const float*)d_in[6];
  const float* Wc2 = (const float*)d_in[7];
  const float* bc2 = (const float*)d_in[8];
  const float* lam = (const float*)d_in[9];
  float* out = (float*)d_out;

  // ws: W1t 1MB | W2t 1MB | Wft 128KB | bcf 2KB
  unsigned short* W1t = (unsigned short*)d_ws;
  unsigned short* W2t = W1t + (size_t)S_N * H_N * D_N;
  unsigned short* Wft = W2t + (size_t)S_N * D_N * H_N;
  float* bcf = (float*)(Wft + (size_t)S_N * K_N * H_N);

  lsi_prep<<<dim3(1152), dim3(256), 0, stream>>>(W1, W2, Wc1, b2, bc1,
                                                 W1t, W2t, Wft, bcf);
  lsi_main<<<dim3(B_N / BT), dim3(512), 0, stream>>>(x, b1, b2, Wc2, bc2, lam,
                                                     W1t, W2t, Wft, bcf, out);
}